// Round 8
// baseline (639.368 us; speedup 1.0000x reference)
//
#include <hip/hip_runtime.h>
#include <hip/hip_bf16.h>

#define HD 256
#define CD 512
#define VD 32000
#define ND 64
#define TD 512

typedef __attribute__((ext_vector_type(8))) short short8;
typedef __attribute__((ext_vector_type(4))) float floatx4;
typedef __attribute__((ext_vector_type(8))) int int32x8;

__device__ inline float bf2f(unsigned short u) {
  union { unsigned u; float f; } t; t.u = ((unsigned)u) << 16; return t.f;
}
__device__ inline unsigned short f2bf(float x) {
  union { float f; unsigned u; } t; t.f = x;
  unsigned u = t.u;
  u += 0x7FFFu + ((u >> 16) & 1u);
  return (unsigned short)(u >> 16);
}
__device__ inline float bf_lo(unsigned u) { union { unsigned u; float f; } t; t.u = u << 16; return t.f; }
__device__ inline float bf_hi(unsigned u) { union { unsigned u; float f; } t; t.u = u & 0xFFFF0000u; return t.f; }

__device__ inline floatx4 zf4() { floatx4 v; v[0] = v[1] = v[2] = v[3] = 0.f; return v; }
__device__ inline floatx4 mfma16(short8 a, short8 b, floatx4 c) {
  return __builtin_amdgcn_mfma_f32_16x16x32_bf16(a, b, c, 0, 0, 0);
}
// MX-scaled fp8 MFMA; scale_a = 1.0 for all K-blocks, scale_b per-lane byte (replicated)
__device__ inline floatx4 mfma_mxs(int32x8 a, int32x8 b, floatx4 c, unsigned sb) {
  return __builtin_amdgcn_mfma_scale_f32_16x16x128_f8f6f4(
      a, b, c, 0, 0, 0, 0x7F7F7F7F, 0, (int)sb);
}

// ---------------- L1: fused start pipeline (block 0) + terminal MLP (blocks 1..512) ----------------
__global__ void k_sm(const float* __restrict__ emb, const float* __restrict__ W,
                     const float* __restrict__ bb, const float* __restrict__ s_rw,
                     const float* __restrict__ s_rb, const float* __restrict__ nextE,
                     float* __restrict__ startO,
                     const float* __restrict__ pretE, const float* __restrict__ t_rw,
                     const float* __restrict__ t_rb, float* __restrict__ fe) {
  __shared__ float x[HD], h[HD];
  __shared__ float lg[2 * HD];
  __shared__ float red[8];
  const int j = threadIdx.x;
  if (blockIdx.x != 0) {
    const int row = blockIdx.x - 1;
    x[j] = pretE[row * HD + j];
    __syncthreads();
    for (int L = 0; L < 2; ++L) {
      const float* w1 = t_rw + (size_t)(L * 2 + 0) * HD * HD;
      const float* b1 = t_rb + (L * 2 + 0) * HD;
      const float* w2 = t_rw + (size_t)(L * 2 + 1) * HD * HD;
      const float* b2 = t_rb + (L * 2 + 1) * HD;
      float a = b1[j];
#pragma unroll 4
      for (int i = 0; i < HD; ++i) a += x[i] * w1[i * HD + j];
      a = fmaxf(a, 0.f);
      h[j] = a;
      __syncthreads();
      float o = b2[j];
#pragma unroll 4
      for (int i = 0; i < HD; ++i) o += h[i] * w2[i * HD + j];
      o = x[j] + fmaxf(o, 0.f);
      __syncthreads();
      x[j] = o;
      __syncthreads();
    }
    fe[row * HD + j] = x[j];
    return;
  }
  x[j] = emb[j];
  __syncthreads();
  float a = bb[j];
#pragma unroll 8
  for (int i = 0; i < HD; ++i) a += x[i] * W[i * HD + j];
  __syncthreads();
  x[j] = a;
  __syncthreads();
  for (int L = 0; L < 2; ++L) {
    const float* w1 = s_rw + (size_t)(L * 2 + 0) * HD * HD;
    const float* b1 = s_rb + (L * 2 + 0) * HD;
    const float* w2 = s_rw + (size_t)(L * 2 + 1) * HD * HD;
    const float* b2 = s_rb + (L * 2 + 1) * HD;
    float t = b1[j];
#pragma unroll 8
    for (int i = 0; i < HD; ++i) t += x[i] * w1[i * HD + j];
    t = fmaxf(t, 0.f);
    h[j] = t;
    __syncthreads();
    float o = b2[j];
#pragma unroll 8
    for (int i = 0; i < HD; ++i) o += h[i] * w2[i * HD + j];
    o = x[j] + fmaxf(o, 0.f);
    __syncthreads();
    x[j] = o;
    __syncthreads();
  }
  {
    const int w = j >> 6, l = j & 63;
    for (int rr = w * 128; rr < (w + 1) * 128; ++rr) {
      float s = 0.f;
#pragma unroll
      for (int k = 0; k < 4; ++k) s += x[l + k * 64] * nextE[rr * HD + l + k * 64];
#pragma unroll
      for (int off = 32; off >= 1; off >>= 1) s += __shfl_down(s, off);
      if (l == 0) lg[rr] = s;
    }
  }
  __syncthreads();
  float lg0 = lg[j], lg1 = lg[j + 256];
  float m = fmaxf(lg0, lg1);
#pragma unroll
  for (int sh = 1; sh <= 32; sh <<= 1) m = fmaxf(m, __shfl_xor(m, sh));
  if ((j & 63) == 0) red[j >> 6] = m;
  __syncthreads();
  m = fmaxf(fmaxf(red[0], red[1]), fmaxf(red[2], red[3]));
  __syncthreads();
  float s = __expf(lg0 - m) + __expf(lg1 - m);
#pragma unroll
  for (int sh = 1; sh <= 32; sh <<= 1) s += __shfl_xor(s, sh);
  if ((j & 63) == 0) red[j >> 6] = s;
  __syncthreads();
  s = red[0] + red[1] + red[2] + red[3];
  float ls = __logf(s);
  startO[j] = lg0 - m - ls;
  startO[j + 256] = lg1 - m - ls;
}

// ---------------- L2: fused GEMMs ----------------
#define GEMM_LDS (2 * 128 * 528)
__global__ __launch_bounds__(512) void k_gemm2(const float* __restrict__ A0,
                                               const float* __restrict__ B0,
                                               unsigned short* __restrict__ out0,
                                               const float* __restrict__ A1,
                                               const float* __restrict__ B1,
                                               unsigned short* __restrict__ out1) {
  extern __shared__ char smem[];
  char* sA = smem;
  char* sB = smem + 128 * 528;
  const int tid = threadIdx.x;
  const int bx = blockIdx.x;
  const float* A; const float* B; unsigned short* out; int mbase;
  if (bx < 250) { A = A0; B = B0; out = out0; mbase = bx * 128; }
  else          { A = A1; B = B1; out = out1; mbase = (bx - 250) * 128; }
  const int row = tid >> 2, seg = tid & 3;
  {
    const float4* srcA = (const float4*)(A + (size_t)(mbase + row) * HD + seg * 64);
    uint2* dA = (uint2*)(sA + row * 528 + seg * 128);
#pragma unroll
    for (int i = 0; i < 16; ++i) {
      float4 va = srcA[i];
      dA[i] = make_uint2((unsigned)f2bf(va.x) | ((unsigned)f2bf(va.y) << 16),
                         (unsigned)f2bf(va.z) | ((unsigned)f2bf(va.w) << 16));
    }
  }
  const int w = tid >> 6, l = tid & 63, l15 = l & 15, quad = l >> 4;
  const char* arow = sA + (w * 16 + l15) * 528 + quad * 16;
  const char* brow = sB + l15 * 528 + quad * 16;
  for (int ny = 0; ny < 4; ++ny) {
    __syncthreads();
    {
      const float4* srcB = (const float4*)(B + (size_t)(ny * 128 + row) * HD + seg * 64);
      uint2* dB = (uint2*)(sB + row * 528 + seg * 128);
#pragma unroll
      for (int i = 0; i < 16; ++i) {
        float4 vb = srcB[i];
        dB[i] = make_uint2((unsigned)f2bf(vb.x) | ((unsigned)f2bf(vb.y) << 16),
                           (unsigned)f2bf(vb.z) | ((unsigned)f2bf(vb.w) << 16));
      }
    }
    __syncthreads();
    floatx4 acc[8];
#pragma unroll
    for (int nt = 0; nt < 8; ++nt) acc[nt] = zf4();
#pragma unroll
    for (int kc = 0; kc < 8; ++kc) {
      short8 a = *(const short8*)(arow + kc * 64);
#pragma unroll
      for (int nt = 0; nt < 8; ++nt) {
        short8 b = *(const short8*)(brow + nt * 16 * 528 + kc * 64);
        acc[nt] = mfma16(a, b, acc[nt]);
      }
    }
#pragma unroll
    for (int nt = 0; nt < 8; ++nt)
#pragma unroll
      for (int r = 0; r < 4; ++r) {
        int m = mbase + w * 16 + quad * 4 + r;
        int n = ny * 128 + nt * 16 + l15;
        out[(size_t)m * CD + n] = f2bf(acc[nt][r]);
      }
  }
}

// ---------------- L3: transition softmax (0..511) + vocab lse (512..636, last-finisher final) ----------------
__global__ __launch_bounds__(512) void k_sml(const unsigned short* __restrict__ tlg,
                                             unsigned char* __restrict__ P8,
                                             unsigned char* __restrict__ PT8,
                                             const unsigned short* __restrict__ logT,
                                             float* __restrict__ part,
                                             float* __restrict__ lse,
                                             unsigned int* __restrict__ cnt) {
  __shared__ float red[8];
  __shared__ int s_last;
  const int tid = threadIdx.x;
  if (blockIdx.x < 512) {
    const int row = blockIdx.x;
    float v = bf2f(tlg[row * CD + tid]);
    float m = v;
#pragma unroll
    for (int sh = 1; sh <= 32; sh <<= 1) m = fmaxf(m, __shfl_xor(m, sh));
    if ((tid & 63) == 0) red[tid >> 6] = m;
    __syncthreads();
    m = fmaxf(fmaxf(fmaxf(red[0], red[1]), fmaxf(red[2], red[3])),
              fmaxf(fmaxf(red[4], red[5]), fmaxf(red[6], red[7])));
    __syncthreads();
    float e = __expf(v - m);
    float s = e;
#pragma unroll
    for (int sh = 1; sh <= 32; sh <<= 1) s += __shfl_xor(s, sh);
    if ((tid & 63) == 0) red[tid >> 6] = s;
    __syncthreads();
    s = red[0] + red[1] + red[2] + red[3] + red[4] + red[5] + red[6] + red[7];
    float inv = 512.0f / s;  // gamma_P = 512
    int b0 = __builtin_amdgcn_cvt_pk_fp8_f32(e * inv, e * inv, 0, false);
    unsigned char byte = (unsigned char)(b0 & 0xff);
    P8[row * CD + tid] = byte;
    PT8[(size_t)tid * CD + row] = byte;
    return;
  }
  const int b = blockIdx.x - 512, c = tid;
  {
    const unsigned short* p = logT + (size_t)b * 256 * CD + c;
    float m = -1e30f, s = 0.f;
    for (int i = 0; i < 256; ++i) {
      float v = bf2f(p[(size_t)i * CD]);
      float nm = fmaxf(m, v);
      s = s * __expf(m - nm) + __expf(v - nm);
      m = nm;
    }
    part[b * 1024 + c] = m;
    part[b * 1024 + 512 + c] = s;
  }
  __threadfence();
  if (tid == 0) s_last = (atomicAdd(cnt, 1u) == 124u) ? 1 : 0;
  __syncthreads();
  if (s_last) {
    __threadfence();
    float m = -1e30f, s = 0.f;
    for (int i = 0; i < 125; ++i) {
      float mi = part[i * 1024 + c], si = part[i * 1024 + 512 + c];
      float nm = fmaxf(m, mi);
      s = s * __expf(m - nm) + si * __expf(mi - nm);
      m = nm;
    }
    lse[c] = m + __logf(s);
  }
}

// ---------------- L4: the scan, 16 blocks, MX per-block scales, inline emission ----------------
// alpha stored fp8 + per-(seq, 32-c-block) E8M0 scale byte (LDS table, double buffered).
// Per-seq integer recenter delta from previous step's bytes (no cross-wave float max,
// no log/Msum per step). E = exp2(log2(e)*(logT-lse) + 14) inline, prefetched 1 step.
// acc[] / E[] arrays: constant indices only (R5 lesson).
__global__ __launch_bounds__(512, 2) void k_scan(const unsigned char* __restrict__ P8,
                                                 const unsigned char* __restrict__ PT8,
                                                 const unsigned short* __restrict__ logT,
                                                 const float* __restrict__ lse,
                                                 const int* __restrict__ text,
                                                 const float* __restrict__ startv,
                                                 float* __restrict__ alphaF,
                                                 float* __restrict__ alphaB,
                                                 unsigned int* __restrict__ cnt,
                                                 float* __restrict__ out) {
  __shared__ unsigned char Abuf[2 * 8 * 512];  // [buf][seq][c fp8], XOR-swizzled 16B units
  __shared__ unsigned char Tbuf[2 * 128];      // [buf][quad'][seq][kc] scale bytes
  __shared__ int txtL[8 * 272];                // [seq][t 0..256]
  __shared__ float scr[8];
  __shared__ int s_last;
  const int g = blockIdx.x, dir = g >> 3, q = g & 7;
  const int tid = threadIdx.x, w = tid >> 6, l = tid & 63;
  const int l15 = l & 15, quad = l >> 4;
  const int r7 = l15 & 7, sel = l15 >> 3;
  const int colbase = w * 64;
  const int c0 = colbase + sel * 32 + quad * 4;
  const unsigned char* Pb = dir ? P8 : PT8;

  // P fragments (A-operand), x512-scaled fp8
  int32x8 Prf[4][4];
#pragma unroll
  for (int kc = 0; kc < 4; ++kc)
#pragma unroll
    for (int mt = 0; mt < 4; ++mt) {
      const uint4* p = (const uint4*)(Pb + (size_t)(colbase + mt * 16 + l15) * CD + kc * 128 + quad * 32);
      uint4 x0 = p[0], x1 = p[1];
      Prf[kc][mt] = (int32x8){(int)x0.x, (int)x0.y, (int)x0.z, (int)x0.w,
                              (int)x1.x, (int)x1.y, (int)x1.z, (int)x1.w};
    }

  // text preload: txtL[r][t] = text[(q*8+r)*TD + (dir? 511-t : t)], t=0..256
  for (int i = tid; i < 8 * 257; i += 512) {
    int r = i / 257, t = i - r * 257;
    int tg = dir ? (511 - t) : t;
    txtL[r * 272 + t] = text[(q * 8 + r) * TD + tg];
  }
  // lse preload (per-lane constants)
  const float4 ls0 = *(const float4*)(lse + c0);
  const float4 ls1 = *(const float4*)(lse + c0 + 16);
  __syncthreads();

  const int wrofs0 = r7 * 512 + (((w * 4 + sel * 2 + 0) ^ r7) << 4) + quad * 4;
  const int wrofs1 = r7 * 512 + (((w * 4 + sel * 2 + 1) ^ r7) << 4) + quad * 4;
  const int twofs = ((w & 1) * 2 + sel) * 32 + r7 * 4 + (w >> 1);
  const int trofs = (quad * 8 + r7) * 4;

  int SA = 0;
  const float LN2 = 0.69314718056f;
  const float L2E = 1.44269504089f;

  // tail: quantize v[8] into fp8 + scale byte for block (w*2+sel), write to buffer wp
  auto tail = [&](float* v, int delta, int wp) {
    float m = fmaxf(fmaxf(fmaxf(v[0], v[1]), fmaxf(v[2], v[3])),
                    fmaxf(fmaxf(v[4], v[5]), fmaxf(v[6], v[7])));
    m = fmaxf(m, __shfl_xor(m, 16));
    m = fmaxf(m, __shfl_xor(m, 32));
    int eb = (int)((__float_as_uint(m) >> 23) & 255) - 127;
    float inv = __uint_as_float((unsigned)(134 - eb) << 23);  // 2^(7-eb)
    int byte = eb + 120 - delta;
    byte = byte < 1 ? 1 : (byte > 254 ? 254 : byte);
    int pk0 = __builtin_amdgcn_cvt_pk_fp8_f32(v[0] * inv, v[1] * inv, 0, false);
    pk0 = __builtin_amdgcn_cvt_pk_fp8_f32(v[2] * inv, v[3] * inv, pk0, true);
    int pk1 = __builtin_amdgcn_cvt_pk_fp8_f32(v[4] * inv, v[5] * inv, 0, false);
    pk1 = __builtin_amdgcn_cvt_pk_fp8_f32(v[6] * inv, v[7] * inv, pk1, true);
    unsigned char* base = Abuf + wp * 4096;
    *(int*)(base + wrofs0) = pk0;
    *(int*)(base + wrofs1) = pk1;
    if (quad == 0) Tbuf[wp * 128 + twofs] = (unsigned char)byte;
    __syncthreads();
  };

  float Ec[8];
  // ---- init tail (t=0): v = exp(start)*E0 (fwd) or E0 (bwd); writes buffer 0
  {
    int tok = txtL[r7 * 272 + 0];
    const unsigned short* rowp = logT + (size_t)tok * CD;
    uint2 ra = *(const uint2*)(rowp + c0);
    uint2 rb = *(const uint2*)(rowp + c0 + 16);
    float v[8];
    v[0] = exp2f((bf_lo(ra.x) - ls0.x) * L2E + 14.f);
    v[1] = exp2f((bf_hi(ra.x) - ls0.y) * L2E + 14.f);
    v[2] = exp2f((bf_lo(ra.y) - ls0.z) * L2E + 14.f);
    v[3] = exp2f((bf_hi(ra.y) - ls0.w) * L2E + 14.f);
    v[4] = exp2f((bf_lo(rb.x) - ls1.x) * L2E + 14.f);
    v[5] = exp2f((bf_hi(rb.x) - ls1.y) * L2E + 14.f);
    v[6] = exp2f((bf_lo(rb.y) - ls1.z) * L2E + 14.f);
    v[7] = exp2f((bf_hi(rb.y) - ls1.w) * L2E + 14.f);
    if (!dir) {
      const float4 s0 = *(const float4*)(startv + c0);
      const float4 s1 = *(const float4*)(startv + c0 + 16);
      v[0] *= __expf(s0.x); v[1] *= __expf(s0.y); v[2] *= __expf(s0.z); v[3] *= __expf(s0.w);
      v[4] *= __expf(s1.x); v[5] *= __expf(s1.y); v[6] *= __expf(s1.z); v[7] *= __expf(s1.w);
    }
    tail(v, 0, 0);
    // E for step 1
    tok = txtL[r7 * 272 + 1];
    rowp = logT + (size_t)tok * CD;
    ra = *(const uint2*)(rowp + c0);
    rb = *(const uint2*)(rowp + c0 + 16);
    Ec[0] = exp2f((bf_lo(ra.x) - ls0.x) * L2E + 14.f);
    Ec[1] = exp2f((bf_hi(ra.x) - ls0.y) * L2E + 14.f);
    Ec[2] = exp2f((bf_lo(ra.y) - ls0.z) * L2E + 14.f);
    Ec[3] = exp2f((bf_hi(ra.y) - ls0.w) * L2E + 14.f);
    Ec[4] = exp2f((bf_lo(rb.x) - ls1.x) * L2E + 14.f);
    Ec[5] = exp2f((bf_hi(rb.x) - ls1.y) * L2E + 14.f);
    Ec[6] = exp2f((bf_lo(rb.y) - ls1.z) * L2E + 14.f);
    Ec[7] = exp2f((bf_hi(rb.y) - ls1.w) * L2E + 14.f);
  }

  const int nloop = dir ? 255 : 254;
  for (int s = 1; s <= nloop; ++s) {
    const int rp = (s & 1) ^ 1;  // read parity (tail s-1 wrote (s-1)&1 = rp)
    // scale word + per-seq recenter delta from previous bytes
    const int Tword = *(const int*)(Tbuf + rp * 128 + trofs);
    int b0 = Tword & 255, b1 = (Tword >> 8) & 255, b2 = (Tword >> 16) & 255, b3 = (Tword >> 24) & 255;
    int bm = max(max(b0, b1), max(b2, b3));
    bm = max(bm, __shfl_xor(bm, 16));
    bm = max(bm, __shfl_xor(bm, 32));
    const int delta = bm - 120;
    const unsigned sb0 = (unsigned)b0 * 0x01010101u;
    const unsigned sb1 = (unsigned)b1 * 0x01010101u;
    const unsigned sb2 = (unsigned)b2 * 0x01010101u;
    const unsigned sb3 = (unsigned)b3 * 0x01010101u;
    // alpha B-fragments
    const unsigned char* rdrow = Abuf + rp * 4096 + r7 * 512;
    int32x8 bfr[4];
#pragma unroll
    for (int kc = 0; kc < 4; ++kc) {
      int u0 = kc * 8 + quad * 2;
      uint4 x0 = *(const uint4*)(rdrow + (((u0 + 0) ^ r7) << 4));
      uint4 x1 = *(const uint4*)(rdrow + (((u0 + 1) ^ r7) << 4));
      bfr[kc] = (int32x8){(int)x0.x, (int)x0.y, (int)x0.z, (int)x0.w,
                          (int)x1.x, (int)x1.y, (int)x1.z, (int)x1.w};
    }
    // prefetch next step's emission row
    int tokn = txtL[r7 * 272 + s + 1];
    const unsigned short* rowp = logT + (size_t)tokn * CD;
    uint2 rna = *(const uint2*)(rowp + c0);
    uint2 rnb = *(const uint2*)(rowp + c0 + 16);
    floatx4 acc[4];
#pragma unroll
    for (int mt = 0; mt < 4; ++mt) acc[mt] = zf4();
    acc[0] = mfma_mxs(Prf[0][0], bfr[0], acc[0], sb0);
    acc[1] = mfma_mxs(Prf[0][1], bfr[0], acc[1], sb0);
    acc[2] = mfma_mxs(Prf[0][2], bfr[0], acc[2], sb0);
    acc[3] = mfma_mxs(Prf[0][3], bfr[0], acc[3], sb0);
    acc[0] = mfma_mxs(Prf[1][0], bfr[1], acc[0], sb1);
    acc[1] = mfma_mxs(Prf[1][1], bfr[1], acc[1], sb1);
    acc[2] = mfma_mxs(Prf[1][2], bfr[1], acc[2], sb1);
    acc[3] = mfma_mxs(Prf[1][3], bfr[1], acc[3], sb1);
    acc[0] = mfma_mxs(Prf[2][0], bfr[2], acc[0], sb2);
    acc[1] = mfma_mxs(Prf[2][1], bfr[2], acc[1], sb2);
    acc[2] = mfma_mxs(Prf[2][2], bfr[2], acc[2], sb2);
    acc[3] = mfma_mxs(Prf[2][3], bfr[2], acc[3], sb2);
    acc[0] = mfma_mxs(Prf[3][0], bfr[3], acc[0], sb3);
    acc[1] = mfma_mxs(Prf[3][1], bfr[3], acc[1], sb3);
    acc[2] = mfma_mxs(Prf[3][2], bfr[3], acc[2], sb3);
    acc[3] = mfma_mxs(Prf[3][3], bfr[3], acc[3], sb3);
    // next-step E (overlaps MFMA)
    float En[8];
    En[0] = exp2f((bf_lo(rna.x) - ls0.x) * L2E + 14.f);
    En[1] = exp2f((bf_hi(rna.x) - ls0.y) * L2E + 14.f);
    En[2] = exp2f((bf_lo(rna.y) - ls0.z) * L2E + 14.f);
    En[3] = exp2f((bf_hi(rna.y) - ls0.w) * L2E + 14.f);
    En[4] = exp2f((bf_lo(rnb.x) - ls1.x) * L2E + 14.f);
    En[5] = exp2f((bf_hi(rnb.x) - ls1.y) * L2E + 14.f);
    En[6] = exp2f((bf_lo(rnb.y) - ls1.z) * L2E + 14.f);
    En[7] = exp2f((bf_hi(rnb.y) - ls1.w) * L2E + 14.f);
    float v[8];
#pragma unroll
    for (int i = 0; i < 2; ++i)
#pragma unroll
      for (int r = 0; r < 4; ++r) {
        int jj = i * 4 + r;
        float a0 = (i == 0) ? acc[0][r] : acc[1][r];
        float a1 = (i == 0) ? acc[2][r] : acc[3][r];
        v[jj] = (sel ? a1 : a0) * Ec[jj];
      }
    SA += delta;
    tail(v, delta, s & 1);
#pragma unroll
    for (int i = 0; i < 8; ++i) Ec[i] = En[i];
  }
  // ---- final step (fwd: s=255 with E; bwd: s=256, E=1) + store
  {
    const int rp = nloop & 1;
    const int Tword = *(const int*)(Tbuf + rp * 128 + trofs);
    int b0 = Tword & 255, b1 = (Tword >> 8) & 255, b2 = (Tword >> 16) & 255, b3 = (Tword >> 24) & 255;
    const unsigned sb0 = (unsigned)b0 * 0x01010101u;
    const unsigned sb1 = (unsigned)b1 * 0x01010101u;
    const unsigned sb2 = (unsigned)b2 * 0x01010101u;
    const unsigned sb3 = (unsigned)b3 * 0x01010101u;
    const unsigned char* rdrow = Abuf + rp * 4096 + r7 * 512;
    int32x8 bfr[4];
#pragma unroll
    for (int kc = 0; kc < 4; ++kc) {
      int u0 = kc * 8 + quad * 2;
      uint4 x0 = *(const uint4*)(rdrow + (((u0 + 0) ^ r7) << 4));
      uint4 x1 = *(const uint4*)(rdrow + (((u0 + 1) ^ r7) << 4));
      bfr[kc] = (int32x8){(int)x0.x, (int)x0.y, (int)x0.z, (int)x0.w,
                          (int)x1.x, (int)x1.y, (int)x1.z, (int)x1.w};
    }
    floatx4 acc[4];
#pragma unroll
    for (int mt = 0; mt < 4; ++mt) acc[mt] = zf4();
    acc[0] = mfma_mxs(Prf[0][0], bfr[0], acc[0], sb0);
    acc[1] = mfma_mxs(Prf[0][1], bfr[0], acc[1], sb0);
    acc[2] = mfma_mxs(Prf[0][2], bfr[0], acc[2], sb0);
    acc[3] = mfma_mxs(Prf[0][3], bfr[0], acc[3], sb0);
    acc[0] = mfma_mxs(Prf[1][0], bfr[1], acc[0], sb1);
    acc[1] = mfma_mxs(Prf[1][1], bfr[1], acc[1], sb1);
    acc[2] = mfma_mxs(Prf[1][2], bfr[1], acc[2], sb1);
    acc[3] = mfma_mxs(Prf[1][3], bfr[1], acc[3], sb1);
    acc[0] = mfma_mxs(Prf[2][0], bfr[2], acc[0], sb2);
    acc[1] = mfma_mxs(Prf[2][1], bfr[2], acc[1], sb2);
    acc[2] = mfma_mxs(Prf[2][2], bfr[2], acc[2], sb2);
    acc[3] = mfma_mxs(Prf[2][3], bfr[2], acc[3], sb2);
    acc[0] = mfma_mxs(Prf[3][0], bfr[3], acc[0], sb3);
    acc[1] = mfma_mxs(Prf[3][1], bfr[3], acc[1], sb3);
    acc[2] = mfma_mxs(Prf[3][2], bfr[3], acc[2], sb3);
    acc[3] = mfma_mxs(Prf[3][3], bfr[3], acc[3], sb3);
    const float C = dir ? 5888.f : 5879.f;  // 9*#P + 14*#E
    const float off = LN2 * ((float)SA - C);
    float* dst = dir ? alphaB : alphaF;
#pragma unroll
    for (int i = 0; i < 2; ++i) {
      float vv[4];
#pragma unroll
      for (int r = 0; r < 4; ++r) {
        int jj = i * 4 + r;
        float E = dir ? 1.f : Ec[jj];
        float a0 = (i == 0) ? acc[0][r] : acc[1][r];
        float a1 = (i == 0) ? acc[2][r] : acc[3][r];
        vv[r] = (sel ? a1 : a0) * E;
      }
      float4 ov;
      ov.x = __logf(vv[0]) + off;
      ov.y = __logf(vv[1]) + off;
      ov.z = __logf(vv[2]) + off;
      ov.w = __logf(vv[3]) + off;
      *(float4*)&dst[(size_t)(q * 8 + r7) * CD + c0 + i * 16] = ov;
    }
  }
  // ---- last-finisher meet
  __threadfence();
  if (tid == 0) s_last = (atomicAdd(cnt, 1u) == 15u) ? 1 : 0;
  __syncthreads();
  if (s_last) {
    __threadfence();
    float ev = 0.f;
    for (int i = 0; i < 8; ++i) {
      int n = w * 8 + i;
      float x[8];
      float m = -1e30f;
#pragma unroll
      for (int k = 0; k < 8; ++k) {
        x[k] = alphaF[n * CD + k * 64 + l] + alphaB[n * CD + k * 64 + l];
        m = fmaxf(m, x[k]);
      }
#pragma unroll
      for (int sh = 1; sh <= 32; sh <<= 1) m = fmaxf(m, __shfl_xor(m, sh));
      float s = 0.f;
#pragma unroll
      for (int k = 0; k < 8; ++k) s += __expf(x[k] - m);
#pragma unroll
      for (int sh = 1; sh <= 32; sh <<= 1) s += __shfl_xor(s, sh);
      ev += m + __logf(s);
    }
    if (l == 0) scr[w] = ev;
    __syncthreads();
    if (tid == 0) {
      float tot = 0.f;
      for (int i = 0; i < 8; ++i) tot += scr[i];
      out[0] = tot;
    }
  }
}

// ---------------- host ----------------
extern "C" void kernel_launch(void* const* d_in, const int* in_sizes, int n_in,
                              void* d_out, int out_size, void* d_ws, size_t ws_size,
                              hipStream_t stream) {
  (void)in_sizes; (void)n_in; (void)out_size;
  const int* text = (const int*)d_in[0];
  const float* s_emb = (const float*)d_in[1];
  const float* s_w = (const float*)d_in[2];
  const float* s_b = (const float*)d_in[3];
  const float* s_rw = (const float*)d_in[4];
  const float* s_rb = (const float*)d_in[5];
  const float* stateE = (const float*)d_in[6];
  const float* nextE = (const float*)d_in[7];
  const float* pretE = (const float*)d_in[8];
  const float* t_rw = (const float*)d_in[9];
  const float* t_rb = (const float*)d_in[10];
  const float* termE = (const float*)d_in[11];
  float* out = (float*)d_out;

  char* ws = (char*)d_ws;
  size_t off = 0;
  auto alloc = [&](size_t bytes) {
    void* p = ws + off;
    off = (off + bytes + 255) & ~(size_t)255;
    return p;
  };
  unsigned int* w_cnt = (unsigned int*)alloc(256);  // [0]=scan, [1]=lsep
  float* w_start = (float*)alloc(CD * 4);
  unsigned short* w_tlg = (unsigned short*)alloc((size_t)CD * CD * 2);
  unsigned char* w_P8 = (unsigned char*)alloc((size_t)CD * CD);
  unsigned char* w_PT8 = (unsigned char*)alloc((size_t)CD * CD);
  float* w_fe = (float*)alloc((size_t)CD * HD * 4);
  unsigned short* w_logT = (unsigned short*)alloc((size_t)VD * CD * 2);
  float* w_part = (float*)alloc((size_t)125 * 1024 * 4);
  float* w_lse = (float*)alloc(CD * 4);
  float* w_aF = (float*)alloc((size_t)ND * CD * 4);
  float* w_aB = (float*)alloc((size_t)ND * CD * 4);
  if (off > ws_size) return;

  hipFuncSetAttribute(reinterpret_cast<const void*>(k_gemm2),
                      hipFuncAttributeMaxDynamicSharedMemorySize, GEMM_LDS);

  hipMemsetAsync(w_cnt, 0, 256, stream);

  k_sm<<<513, 256, 0, stream>>>(s_emb, s_w, s_b, s_rw, s_rb, nextE, w_start,
                                pretE, t_rw, t_rb, w_fe);
  k_gemm2<<<254, 512, GEMM_LDS, stream>>>(termE, w_fe, w_logT, stateE, nextE, w_tlg);
  k_sml<<<637, 512, 0, stream>>>(w_tlg, w_P8, w_PT8, w_logT, w_part, w_lse, w_cnt + 1);
  k_scan<<<16, 512, 0, stream>>>(w_P8, w_PT8, w_logT, w_lse, text, w_start,
                                 w_aF, w_aB, w_cnt, out);
}

// Round 9
// 583.246 us; speedup vs baseline: 1.0962x; 1.0962x over previous
//
#include <hip/hip_runtime.h>
#include <hip/hip_bf16.h>

#define HD 256
#define CD 512
#define VD 32000
#define ND 64
#define TD 512

typedef __attribute__((ext_vector_type(8))) short short8;
typedef __attribute__((ext_vector_type(4))) float floatx4;
typedef __attribute__((ext_vector_type(8))) int int32x8;

__device__ inline float bf2f(unsigned short u) {
  union { unsigned u; float f; } t; t.u = ((unsigned)u) << 16; return t.f;
}
__device__ inline unsigned short f2bf(float x) {
  union { float f; unsigned u; } t; t.f = x;
  unsigned u = t.u;
  u += 0x7FFFu + ((u >> 16) & 1u);
  return (unsigned short)(u >> 16);
}
__device__ inline float bf_lo(unsigned u) { union { unsigned u; float f; } t; t.u = u << 16; return t.f; }
__device__ inline float bf_hi(unsigned u) { union { unsigned u; float f; } t; t.u = u & 0xFFFF0000u; return t.f; }

__device__ inline floatx4 zf4() { floatx4 v; v[0] = v[1] = v[2] = v[3] = 0.f; return v; }
__device__ inline floatx4 mfma16(short8 a, short8 b, floatx4 c) {
  return __builtin_amdgcn_mfma_f32_16x16x32_bf16(a, b, c, 0, 0, 0);
}
// MX-scaled fp8 MFMA; scale_a = 1.0 for all K-blocks, scale_b per-lane byte (replicated)
__device__ inline floatx4 mfma_mxs(int32x8 a, int32x8 b, floatx4 c, unsigned sb) {
  return __builtin_amdgcn_mfma_scale_f32_16x16x128_f8f6f4(
      a, b, c, 0, 0, 0, 0x7F7F7F7F, 0, (int)sb);
}

// ---------------- L1: start pipeline (block 0) + terminal MLP (1..512) + cnt zero (513) ----------------
__global__ void k_sm(const float* __restrict__ emb, const float* __restrict__ W,
                     const float* __restrict__ bb, const float* __restrict__ s_rw,
                     const float* __restrict__ s_rb, const float* __restrict__ nextE,
                     float* __restrict__ startO,
                     const float* __restrict__ pretE, const float* __restrict__ t_rw,
                     const float* __restrict__ t_rb, float* __restrict__ fe,
                     unsigned int* __restrict__ cnt) {
  __shared__ float x[HD], h[HD];
  __shared__ float lg[2 * HD];
  __shared__ float red[8];
  const int j = threadIdx.x;
  if (blockIdx.x == 513) {
    if (j < 8) cnt[j] = 0u;
    return;
  }
  if (blockIdx.x != 0) {
    const int row = blockIdx.x - 1;
    x[j] = pretE[row * HD + j];
    __syncthreads();
    for (int L = 0; L < 2; ++L) {
      const float* w1 = t_rw + (size_t)(L * 2 + 0) * HD * HD;
      const float* b1 = t_rb + (L * 2 + 0) * HD;
      const float* w2 = t_rw + (size_t)(L * 2 + 1) * HD * HD;
      const float* b2 = t_rb + (L * 2 + 1) * HD;
      float a = b1[j];
#pragma unroll 4
      for (int i = 0; i < HD; ++i) a += x[i] * w1[i * HD + j];
      a = fmaxf(a, 0.f);
      h[j] = a;
      __syncthreads();
      float o = b2[j];
#pragma unroll 4
      for (int i = 0; i < HD; ++i) o += h[i] * w2[i * HD + j];
      o = x[j] + fmaxf(o, 0.f);
      __syncthreads();
      x[j] = o;
      __syncthreads();
    }
    fe[row * HD + j] = x[j];
    return;
  }
  x[j] = emb[j];
  __syncthreads();
  float a = bb[j];
#pragma unroll 8
  for (int i = 0; i < HD; ++i) a += x[i] * W[i * HD + j];
  __syncthreads();
  x[j] = a;
  __syncthreads();
  for (int L = 0; L < 2; ++L) {
    const float* w1 = s_rw + (size_t)(L * 2 + 0) * HD * HD;
    const float* b1 = s_rb + (L * 2 + 0) * HD;
    const float* w2 = s_rw + (size_t)(L * 2 + 1) * HD * HD;
    const float* b2 = s_rb + (L * 2 + 1) * HD;
    float t = b1[j];
#pragma unroll 8
    for (int i = 0; i < HD; ++i) t += x[i] * w1[i * HD + j];
    t = fmaxf(t, 0.f);
    h[j] = t;
    __syncthreads();
    float o = b2[j];
#pragma unroll 8
    for (int i = 0; i < HD; ++i) o += h[i] * w2[i * HD + j];
    o = x[j] + fmaxf(o, 0.f);
    __syncthreads();
    x[j] = o;
    __syncthreads();
  }
  {
    const int w = j >> 6, l = j & 63;
    for (int rr = w * 128; rr < (w + 1) * 128; ++rr) {
      float s = 0.f;
#pragma unroll
      for (int k = 0; k < 4; ++k) s += x[l + k * 64] * nextE[rr * HD + l + k * 64];
#pragma unroll
      for (int off = 32; off >= 1; off >>= 1) s += __shfl_down(s, off);
      if (l == 0) lg[rr] = s;
    }
  }
  __syncthreads();
  float lg0 = lg[j], lg1 = lg[j + 256];
  float m = fmaxf(lg0, lg1);
#pragma unroll
  for (int sh = 1; sh <= 32; sh <<= 1) m = fmaxf(m, __shfl_xor(m, sh));
  if ((j & 63) == 0) red[j >> 6] = m;
  __syncthreads();
  m = fmaxf(fmaxf(red[0], red[1]), fmaxf(red[2], red[3]));
  __syncthreads();
  float s = __expf(lg0 - m) + __expf(lg1 - m);
#pragma unroll
  for (int sh = 1; sh <= 32; sh <<= 1) s += __shfl_xor(s, sh);
  if ((j & 63) == 0) red[j >> 6] = s;
  __syncthreads();
  s = red[0] + red[1] + red[2] + red[3];
  float ls = __logf(s);
  startO[j] = lg0 - m - ls;
  startO[j + 256] = lg1 - m - ls;
}

// ---------------- L2: fused GEMMs ----------------
#define GEMM_LDS (2 * 128 * 528)
__global__ __launch_bounds__(512) void k_gemm2(const float* __restrict__ A0,
                                               const float* __restrict__ B0,
                                               unsigned short* __restrict__ out0,
                                               const float* __restrict__ A1,
                                               const float* __restrict__ B1,
                                               unsigned short* __restrict__ out1) {
  extern __shared__ char smem[];
  char* sA = smem;
  char* sB = smem + 128 * 528;
  const int tid = threadIdx.x;
  const int bx = blockIdx.x;
  const float* A; const float* B; unsigned short* out; int mbase;
  if (bx < 250) { A = A0; B = B0; out = out0; mbase = bx * 128; }
  else          { A = A1; B = B1; out = out1; mbase = (bx - 250) * 128; }
  const int row = tid >> 2, seg = tid & 3;
  {
    const float4* srcA = (const float4*)(A + (size_t)(mbase + row) * HD + seg * 64);
    uint2* dA = (uint2*)(sA + row * 528 + seg * 128);
#pragma unroll
    for (int i = 0; i < 16; ++i) {
      float4 va = srcA[i];
      dA[i] = make_uint2((unsigned)f2bf(va.x) | ((unsigned)f2bf(va.y) << 16),
                         (unsigned)f2bf(va.z) | ((unsigned)f2bf(va.w) << 16));
    }
  }
  const int w = tid >> 6, l = tid & 63, l15 = l & 15, quad = l >> 4;
  const char* arow = sA + (w * 16 + l15) * 528 + quad * 16;
  const char* brow = sB + l15 * 528 + quad * 16;
  for (int ny = 0; ny < 4; ++ny) {
    __syncthreads();
    {
      const float4* srcB = (const float4*)(B + (size_t)(ny * 128 + row) * HD + seg * 64);
      uint2* dB = (uint2*)(sB + row * 528 + seg * 128);
#pragma unroll
      for (int i = 0; i < 16; ++i) {
        float4 vb = srcB[i];
        dB[i] = make_uint2((unsigned)f2bf(vb.x) | ((unsigned)f2bf(vb.y) << 16),
                           (unsigned)f2bf(vb.z) | ((unsigned)f2bf(vb.w) << 16));
      }
    }
    __syncthreads();
    floatx4 acc[8];
#pragma unroll
    for (int nt = 0; nt < 8; ++nt) acc[nt] = zf4();
#pragma unroll
    for (int kc = 0; kc < 8; ++kc) {
      short8 a = *(const short8*)(arow + kc * 64);
#pragma unroll
      for (int nt = 0; nt < 8; ++nt) {
        short8 b = *(const short8*)(brow + nt * 16 * 528 + kc * 64);
        acc[nt] = mfma16(a, b, acc[nt]);
      }
    }
#pragma unroll
    for (int nt = 0; nt < 8; ++nt)
#pragma unroll
      for (int r = 0; r < 4; ++r) {
        int m = mbase + w * 16 + quad * 4 + r;
        int n = ny * 128 + nt * 16 + l15;
        out[(size_t)m * CD + n] = f2bf(acc[nt][r]);
      }
  }
}

// ---------------- L3: transition softmax (0..511) + vocab lse (512..636, last-finisher final) ----------------
__global__ __launch_bounds__(512) void k_sml(const unsigned short* __restrict__ tlg,
                                             unsigned char* __restrict__ P8,
                                             unsigned char* __restrict__ PT8,
                                             const unsigned short* __restrict__ logT,
                                             float* __restrict__ part,
                                             float* __restrict__ lse,
                                             unsigned int* __restrict__ cnt) {
  __shared__ float red[8];
  __shared__ int s_last;
  const int tid = threadIdx.x;
  if (blockIdx.x < 512) {
    const int row = blockIdx.x;
    float v = bf2f(tlg[row * CD + tid]);
    float m = v;
#pragma unroll
    for (int sh = 1; sh <= 32; sh <<= 1) m = fmaxf(m, __shfl_xor(m, sh));
    if ((tid & 63) == 0) red[tid >> 6] = m;
    __syncthreads();
    m = fmaxf(fmaxf(fmaxf(red[0], red[1]), fmaxf(red[2], red[3])),
              fmaxf(fmaxf(red[4], red[5]), fmaxf(red[6], red[7])));
    __syncthreads();
    float e = __expf(v - m);
    float s = e;
#pragma unroll
    for (int sh = 1; sh <= 32; sh <<= 1) s += __shfl_xor(s, sh);
    if ((tid & 63) == 0) red[tid >> 6] = s;
    __syncthreads();
    s = red[0] + red[1] + red[2] + red[3] + red[4] + red[5] + red[6] + red[7];
    float inv = 512.0f / s;  // gamma_P = 512
    int b0 = __builtin_amdgcn_cvt_pk_fp8_f32(e * inv, e * inv, 0, false);
    unsigned char byte = (unsigned char)(b0 & 0xff);
    P8[row * CD + tid] = byte;
    PT8[(size_t)tid * CD + row] = byte;
    return;
  }
  const int b = blockIdx.x - 512, c = tid;
  {
    const unsigned short* p = logT + (size_t)b * 256 * CD + c;
    float m = -1e30f, s = 0.f;
    for (int i = 0; i < 256; ++i) {
      float v = bf2f(p[(size_t)i * CD]);
      float nm = fmaxf(m, v);
      s = s * __expf(m - nm) + __expf(v - nm);
      m = nm;
    }
    part[b * 1024 + c] = m;
    part[b * 1024 + 512 + c] = s;
  }
  __threadfence();
  if (tid == 0) s_last = (atomicAdd(cnt, 1u) == 124u) ? 1 : 0;
  __syncthreads();
  if (s_last) {
    __threadfence();
    float m = -1e30f, s = 0.f;
    for (int i = 0; i < 125; ++i) {
      float mi = part[i * 1024 + c], si = part[i * 1024 + 512 + c];
      float nm = fmaxf(m, mi);
      s = s * __expf(m - nm) + si * __expf(mi - nm);
      m = nm;
    }
    lse[c] = m + __logf(s);
  }
}

// ---------------- L4: the scan, 16 blocks, MX per-block scales, 2-step-pipelined inline emission ----------------
// alpha fp8 + per-(seq, 32-c-block) E8M0 scale byte; per-seq integer recenter.
// Emission row for step s+2 LOADED at iteration s (raw regs), exp2'd at s+1, consumed at s+2:
// full-step latency tolerance, no vmcnt stall on the critical path (the R8 regression).
// acc[]/E[] arrays: constant indices only (R5 lesson).
__global__ __launch_bounds__(512, 2) void k_scan(const unsigned char* __restrict__ P8,
                                                 const unsigned char* __restrict__ PT8,
                                                 const unsigned short* __restrict__ logT,
                                                 const float* __restrict__ lse,
                                                 const int* __restrict__ text,
                                                 const float* __restrict__ startv,
                                                 float* __restrict__ alphaF,
                                                 float* __restrict__ alphaB,
                                                 unsigned int* __restrict__ cnt,
                                                 float* __restrict__ out) {
  __shared__ unsigned char Abuf[2 * 8 * 512];  // [buf][seq][c fp8], XOR-swizzled 16B units
  __shared__ unsigned char Tbuf[2 * 128];      // [buf][cb%4][seq][cb/4] scale bytes
  __shared__ int txtL[8 * 272];                // [seq][t 0..256]
  __shared__ float scr[8];
  __shared__ int s_last;
  const int g = blockIdx.x, dir = g >> 3, q = g & 7;
  const int tid = threadIdx.x, w = tid >> 6, l = tid & 63;
  const int l15 = l & 15, quad = l >> 4;
  const int r7 = l15 & 7, sel = l15 >> 3;
  const int colbase = w * 64;
  const int c0 = colbase + sel * 32 + quad * 4;
  const unsigned char* Pb = dir ? P8 : PT8;

  // P fragments (A-operand), x512-scaled fp8
  int32x8 Prf[4][4];
#pragma unroll
  for (int kc = 0; kc < 4; ++kc)
#pragma unroll
    for (int mt = 0; mt < 4; ++mt) {
      const uint4* p = (const uint4*)(Pb + (size_t)(colbase + mt * 16 + l15) * CD + kc * 128 + quad * 32);
      uint4 x0 = p[0], x1 = p[1];
      Prf[kc][mt] = (int32x8){(int)x0.x, (int)x0.y, (int)x0.z, (int)x0.w,
                              (int)x1.x, (int)x1.y, (int)x1.z, (int)x1.w};
    }

  for (int i = tid; i < 8 * 257; i += 512) {
    int r = i / 257, t = i - r * 257;
    int tg = dir ? (511 - t) : t;
    txtL[r * 272 + t] = text[(q * 8 + r) * TD + tg];
  }
  const float4 ls0 = *(const float4*)(lse + c0);
  const float4 ls1 = *(const float4*)(lse + c0 + 16);
  __syncthreads();

  const int wrofs0 = r7 * 512 + (((w * 4 + sel * 2 + 0) ^ r7) << 4) + quad * 4;
  const int wrofs1 = r7 * 512 + (((w * 4 + sel * 2 + 1) ^ r7) << 4) + quad * 4;
  const int twofs = ((w & 1) * 2 + sel) * 32 + r7 * 4 + (w >> 1);
  const int trofs = (quad * 8 + r7) * 4;

  int SA = 0;
  const float LN2 = 0.69314718056f;
  const float L2E = 1.44269504089f;

  auto tail = [&](float* v, int delta, int wp) {
    float m = fmaxf(fmaxf(fmaxf(v[0], v[1]), fmaxf(v[2], v[3])),
                    fmaxf(fmaxf(v[4], v[5]), fmaxf(v[6], v[7])));
    m = fmaxf(m, __shfl_xor(m, 16));
    m = fmaxf(m, __shfl_xor(m, 32));
    int eb = (int)((__float_as_uint(m) >> 23) & 255) - 127;
    float inv = __uint_as_float((unsigned)(134 - eb) << 23);  // 2^(7-eb)
    int byte = eb + 120 - delta;
    byte = byte < 1 ? 1 : (byte > 254 ? 254 : byte);
    int pk0 = __builtin_amdgcn_cvt_pk_fp8_f32(v[0] * inv, v[1] * inv, 0, false);
    pk0 = __builtin_amdgcn_cvt_pk_fp8_f32(v[2] * inv, v[3] * inv, pk0, true);
    int pk1 = __builtin_amdgcn_cvt_pk_fp8_f32(v[4] * inv, v[5] * inv, 0, false);
    pk1 = __builtin_amdgcn_cvt_pk_fp8_f32(v[6] * inv, v[7] * inv, pk1, true);
    unsigned char* base = Abuf + wp * 4096;
    *(int*)(base + wrofs0) = pk0;
    *(int*)(base + wrofs1) = pk1;
    if (quad == 0) Tbuf[wp * 128 + twofs] = (unsigned char)byte;
    __syncthreads();
  };

  float Ec[8];       // E for step s (consumed this iteration)
  uint2 rpa, rpb;    // raw row for step s+1 (exp2'd this iteration)
  // ---- init tail (t=0) + pipeline prime
  {
    int tok = txtL[r7 * 272 + 0];
    const unsigned short* rowp = logT + (size_t)tok * CD;
    uint2 ra = *(const uint2*)(rowp + c0);
    uint2 rb = *(const uint2*)(rowp + c0 + 16);
    float v[8];
    v[0] = exp2f((bf_lo(ra.x) - ls0.x) * L2E + 14.f);
    v[1] = exp2f((bf_hi(ra.x) - ls0.y) * L2E + 14.f);
    v[2] = exp2f((bf_lo(ra.y) - ls0.z) * L2E + 14.f);
    v[3] = exp2f((bf_hi(ra.y) - ls0.w) * L2E + 14.f);
    v[4] = exp2f((bf_lo(rb.x) - ls1.x) * L2E + 14.f);
    v[5] = exp2f((bf_hi(rb.x) - ls1.y) * L2E + 14.f);
    v[6] = exp2f((bf_lo(rb.y) - ls1.z) * L2E + 14.f);
    v[7] = exp2f((bf_hi(rb.y) - ls1.w) * L2E + 14.f);
    if (!dir) {
      const float4 s0 = *(const float4*)(startv + c0);
      const float4 s1 = *(const float4*)(startv + c0 + 16);
      v[0] *= __expf(s0.x); v[1] *= __expf(s0.y); v[2] *= __expf(s0.z); v[3] *= __expf(s0.w);
      v[4] *= __expf(s1.x); v[5] *= __expf(s1.y); v[6] *= __expf(s1.z); v[7] *= __expf(s1.w);
    }
    tail(v, 0, 0);
    // Ec = E[1] (one-time immediate use)
    tok = txtL[r7 * 272 + 1];
    rowp = logT + (size_t)tok * CD;
    ra = *(const uint2*)(rowp + c0);
    rb = *(const uint2*)(rowp + c0 + 16);
    Ec[0] = exp2f((bf_lo(ra.x) - ls0.x) * L2E + 14.f);
    Ec[1] = exp2f((bf_hi(ra.x) - ls0.y) * L2E + 14.f);
    Ec[2] = exp2f((bf_lo(ra.y) - ls0.z) * L2E + 14.f);
    Ec[3] = exp2f((bf_hi(ra.y) - ls0.w) * L2E + 14.f);
    Ec[4] = exp2f((bf_lo(rb.x) - ls1.x) * L2E + 14.f);
    Ec[5] = exp2f((bf_hi(rb.x) - ls1.y) * L2E + 14.f);
    Ec[6] = exp2f((bf_lo(rb.y) - ls1.z) * L2E + 14.f);
    Ec[7] = exp2f((bf_hi(rb.y) - ls1.w) * L2E + 14.f);
    // raw row[2] for the pipeline
    tok = txtL[r7 * 272 + 2];
    rowp = logT + (size_t)tok * CD;
    rpa = *(const uint2*)(rowp + c0);
    rpb = *(const uint2*)(rowp + c0 + 16);
  }

  const int nloop = dir ? 255 : 254;
  for (int s = 1; s <= nloop; ++s) {
    const int rp = (s & 1) ^ 1;
    const int Tword = *(const int*)(Tbuf + rp * 128 + trofs);
    int b0 = Tword & 255, b1 = (Tword >> 8) & 255, b2 = (Tword >> 16) & 255, b3 = (Tword >> 24) & 255;
    int bm = max(max(b0, b1), max(b2, b3));
    bm = max(bm, __shfl_xor(bm, 16));
    bm = max(bm, __shfl_xor(bm, 32));
    const int delta = bm - 120;
    const unsigned sb0 = (unsigned)b0 * 0x01010101u;
    const unsigned sb1 = (unsigned)b1 * 0x01010101u;
    const unsigned sb2 = (unsigned)b2 * 0x01010101u;
    const unsigned sb3 = (unsigned)b3 * 0x01010101u;
    const unsigned char* rdrow = Abuf + rp * 4096 + r7 * 512;
    int32x8 bfr[4];
#pragma unroll
    for (int kc = 0; kc < 4; ++kc) {
      int u0 = kc * 8 + quad * 2;
      uint4 x0 = *(const uint4*)(rdrow + (((u0 + 0) ^ r7) << 4));
      uint4 x1 = *(const uint4*)(rdrow + (((u0 + 1) ^ r7) << 4));
      bfr[kc] = (int32x8){(int)x0.x, (int)x0.y, (int)x0.z, (int)x0.w,
                          (int)x1.x, (int)x1.y, (int)x1.z, (int)x1.w};
    }
    // issue load of row[s+2] (consumed at iteration s+1 -> full-step latency slack)
    int idx = s + 2 > 256 ? 256 : s + 2;
    int tokn = txtL[r7 * 272 + idx];
    const unsigned short* rowp = logT + (size_t)tokn * CD;
    uint2 rna = *(const uint2*)(rowp + c0);
    uint2 rnb = *(const uint2*)(rowp + c0 + 16);
    floatx4 acc[4];
#pragma unroll
    for (int mt = 0; mt < 4; ++mt) acc[mt] = zf4();
    acc[0] = mfma_mxs(Prf[0][0], bfr[0], acc[0], sb0);
    acc[1] = mfma_mxs(Prf[0][1], bfr[0], acc[1], sb0);
    acc[2] = mfma_mxs(Prf[0][2], bfr[0], acc[2], sb0);
    acc[3] = mfma_mxs(Prf[0][3], bfr[0], acc[3], sb0);
    acc[0] = mfma_mxs(Prf[1][0], bfr[1], acc[0], sb1);
    acc[1] = mfma_mxs(Prf[1][1], bfr[1], acc[1], sb1);
    acc[2] = mfma_mxs(Prf[1][2], bfr[1], acc[2], sb1);
    acc[3] = mfma_mxs(Prf[1][3], bfr[1], acc[3], sb1);
    acc[0] = mfma_mxs(Prf[2][0], bfr[2], acc[0], sb2);
    acc[1] = mfma_mxs(Prf[2][1], bfr[2], acc[1], sb2);
    acc[2] = mfma_mxs(Prf[2][2], bfr[2], acc[2], sb2);
    acc[3] = mfma_mxs(Prf[2][3], bfr[2], acc[3], sb2);
    acc[0] = mfma_mxs(Prf[3][0], bfr[3], acc[0], sb3);
    acc[1] = mfma_mxs(Prf[3][1], bfr[3], acc[1], sb3);
    acc[2] = mfma_mxs(Prf[3][2], bfr[3], acc[2], sb3);
    acc[3] = mfma_mxs(Prf[3][3], bfr[3], acc[3], sb3);
    // En = E[s+1] from registers loaded LAST iteration (no stall)
    float En[8];
    En[0] = exp2f((bf_lo(rpa.x) - ls0.x) * L2E + 14.f);
    En[1] = exp2f((bf_hi(rpa.x) - ls0.y) * L2E + 14.f);
    En[2] = exp2f((bf_lo(rpa.y) - ls0.z) * L2E + 14.f);
    En[3] = exp2f((bf_hi(rpa.y) - ls0.w) * L2E + 14.f);
    En[4] = exp2f((bf_lo(rpb.x) - ls1.x) * L2E + 14.f);
    En[5] = exp2f((bf_hi(rpb.x) - ls1.y) * L2E + 14.f);
    En[6] = exp2f((bf_lo(rpb.y) - ls1.z) * L2E + 14.f);
    En[7] = exp2f((bf_hi(rpb.y) - ls1.w) * L2E + 14.f);
    float v[8];
#pragma unroll
    for (int i = 0; i < 2; ++i)
#pragma unroll
      for (int r = 0; r < 4; ++r) {
        int jj = i * 4 + r;
        float a0 = (i == 0) ? acc[0][r] : acc[1][r];
        float a1 = (i == 0) ? acc[2][r] : acc[3][r];
        v[jj] = (sel ? a1 : a0) * Ec[jj];
      }
    SA += delta;
    tail(v, delta, s & 1);
#pragma unroll
    for (int i = 0; i < 8; ++i) Ec[i] = En[i];
    rpa = rna; rpb = rnb;
  }
  // ---- final step (fwd: s=255 with E; bwd: s=256, E=1) + store
  {
    const int rp = nloop & 1;
    const int Tword = *(const int*)(Tbuf + rp * 128 + trofs);
    int b0 = Tword & 255, b1 = (Tword >> 8) & 255, b2 = (Tword >> 16) & 255, b3 = (Tword >> 24) & 255;
    const unsigned sb0 = (unsigned)b0 * 0x01010101u;
    const unsigned sb1 = (unsigned)b1 * 0x01010101u;
    const unsigned sb2 = (unsigned)b2 * 0x01010101u;
    const unsigned sb3 = (unsigned)b3 * 0x01010101u;
    const unsigned char* rdrow = Abuf + rp * 4096 + r7 * 512;
    int32x8 bfr[4];
#pragma unroll
    for (int kc = 0; kc < 4; ++kc) {
      int u0 = kc * 8 + quad * 2;
      uint4 x0 = *(const uint4*)(rdrow + (((u0 + 0) ^ r7) << 4));
      uint4 x1 = *(const uint4*)(rdrow + (((u0 + 1) ^ r7) << 4));
      bfr[kc] = (int32x8){(int)x0.x, (int)x0.y, (int)x0.z, (int)x0.w,
                          (int)x1.x, (int)x1.y, (int)x1.z, (int)x1.w};
    }
    floatx4 acc[4];
#pragma unroll
    for (int mt = 0; mt < 4; ++mt) acc[mt] = zf4();
    acc[0] = mfma_mxs(Prf[0][0], bfr[0], acc[0], sb0);
    acc[1] = mfma_mxs(Prf[0][1], bfr[0], acc[1], sb0);
    acc[2] = mfma_mxs(Prf[0][2], bfr[0], acc[2], sb0);
    acc[3] = mfma_mxs(Prf[0][3], bfr[0], acc[3], sb0);
    acc[0] = mfma_mxs(Prf[1][0], bfr[1], acc[0], sb1);
    acc[1] = mfma_mxs(Prf[1][1], bfr[1], acc[1], sb1);
    acc[2] = mfma_mxs(Prf[1][2], bfr[1], acc[2], sb1);
    acc[3] = mfma_mxs(Prf[1][3], bfr[1], acc[3], sb1);
    acc[0] = mfma_mxs(Prf[2][0], bfr[2], acc[0], sb2);
    acc[1] = mfma_mxs(Prf[2][1], bfr[2], acc[1], sb2);
    acc[2] = mfma_mxs(Prf[2][2], bfr[2], acc[2], sb2);
    acc[3] = mfma_mxs(Prf[2][3], bfr[2], acc[3], sb2);
    acc[0] = mfma_mxs(Prf[3][0], bfr[3], acc[0], sb3);
    acc[1] = mfma_mxs(Prf[3][1], bfr[3], acc[1], sb3);
    acc[2] = mfma_mxs(Prf[3][2], bfr[3], acc[2], sb3);
    acc[3] = mfma_mxs(Prf[3][3], bfr[3], acc[3], sb3);
    const float C = dir ? 5888.f : 5879.f;  // 9*#P + 14*#E
    const float off = LN2 * ((float)SA - C);
    float* dst = dir ? alphaB : alphaF;
#pragma unroll
    for (int i = 0; i < 2; ++i) {
      float vv[4];
#pragma unroll
      for (int r = 0; r < 4; ++r) {
        int jj = i * 4 + r;
        float E = dir ? 1.f : Ec[jj];
        float a0 = (i == 0) ? acc[0][r] : acc[1][r];
        float a1 = (i == 0) ? acc[2][r] : acc[3][r];
        vv[r] = (sel ? a1 : a0) * E;
      }
      float4 ov;
      ov.x = __logf(vv[0]) + off;
      ov.y = __logf(vv[1]) + off;
      ov.z = __logf(vv[2]) + off;
      ov.w = __logf(vv[3]) + off;
      *(float4*)&dst[(size_t)(q * 8 + r7) * CD + c0 + i * 16] = ov;
    }
  }
  // ---- last-finisher meet
  __threadfence();
  if (tid == 0) s_last = (atomicAdd(cnt, 1u) == 15u) ? 1 : 0;
  __syncthreads();
  if (s_last) {
    __threadfence();
    float ev = 0.f;
    for (int i = 0; i < 8; ++i) {
      int n = w * 8 + i;
      float x[8];
      float m = -1e30f;
#pragma unroll
      for (int k = 0; k < 8; ++k) {
        x[k] = alphaF[n * CD + k * 64 + l] + alphaB[n * CD + k * 64 + l];
        m = fmaxf(m, x[k]);
      }
#pragma unroll
      for (int sh = 1; sh <= 32; sh <<= 1) m = fmaxf(m, __shfl_xor(m, sh));
      float s = 0.f;
#pragma unroll
      for (int k = 0; k < 8; ++k) s += __expf(x[k] - m);
#pragma unroll
      for (int sh = 1; sh <= 32; sh <<= 1) s += __shfl_xor(s, sh);
      ev += m + __logf(s);
    }
    if (l == 0) scr[w] = ev;
    __syncthreads();
    if (tid == 0) {
      float tot = 0.f;
      for (int i = 0; i < 8; ++i) tot += scr[i];
      out[0] = tot;
    }
  }
}

// ---------------- host ----------------
extern "C" void kernel_launch(void* const* d_in, const int* in_sizes, int n_in,
                              void* d_out, int out_size, void* d_ws, size_t ws_size,
                              hipStream_t stream) {
  (void)in_sizes; (void)n_in; (void)out_size;
  const int* text = (const int*)d_in[0];
  const float* s_emb = (const float*)d_in[1];
  const float* s_w = (const float*)d_in[2];
  const float* s_b = (const float*)d_in[3];
  const float* s_rw = (const float*)d_in[4];
  const float* s_rb = (const float*)d_in[5];
  const float* stateE = (const float*)d_in[6];
  const float* nextE = (const float*)d_in[7];
  const float* pretE = (const float*)d_in[8];
  const float* t_rw = (const float*)d_in[9];
  const float* t_rb = (const float*)d_in[10];
  const float* termE = (const float*)d_in[11];
  float* out = (float*)d_out;

  char* ws = (char*)d_ws;
  size_t off = 0;
  auto alloc = [&](size_t bytes) {
    void* p = ws + off;
    off = (off + bytes + 255) & ~(size_t)255;
    return p;
  };
  unsigned int* w_cnt = (unsigned int*)alloc(256);  // [0]=scan, [1]=lsep
  float* w_start = (float*)alloc(CD * 4);
  unsigned short* w_tlg = (unsigned short*)alloc((size_t)CD * CD * 2);
  unsigned char* w_P8 = (unsigned char*)alloc((size_t)CD * CD);
  unsigned char* w_PT8 = (unsigned char*)alloc((size_t)CD * CD);
  float* w_fe = (float*)alloc((size_t)CD * HD * 4);
  unsigned short* w_logT = (unsigned short*)alloc((size_t)VD * CD * 2);
  float* w_part = (float*)alloc((size_t)125 * 1024 * 4);
  float* w_lse = (float*)alloc(CD * 4);
  float* w_aF = (float*)alloc((size_t)ND * CD * 4);
  float* w_aB = (float*)alloc((size_t)ND * CD * 4);
  if (off > ws_size) return;

  hipFuncSetAttribute(reinterpret_cast<const void*>(k_gemm2),
                      hipFuncAttributeMaxDynamicSharedMemorySize, GEMM_LDS);

  k_sm<<<514, 256, 0, stream>>>(s_emb, s_w, s_b, s_rw, s_rb, nextE, w_start,
                                pretE, t_rw, t_rb, w_fe, w_cnt);
  k_gemm2<<<254, 512, GEMM_LDS, stream>>>(termE, w_fe, w_logT, stateE, nextE, w_tlg);
  k_sml<<<637, 512, 0, stream>>>(w_tlg, w_P8, w_PT8, w_logT, w_part, w_lse, w_cnt + 1);
  k_scan<<<16, 512, 0, stream>>>(w_P8, w_PT8, w_logT, w_lse, text, w_start,
                                 w_aF, w_aB, w_cnt, out);
}